// Round 4
// baseline (451.861 us; speedup 1.0000x reference)
//
#include <hip/hip_runtime.h>
#include <hip/hip_bf16.h>

#define HH 56
#define WW 56
#define HW 3136
#define CIN 256
#define COUT 512
#define NBATCH 32
#define EPS 1e-5f
#define DW_TH 4.0f
#define PW_TH 1e-3f

#define CG 32            // channels per dw block
#define CPITCH 508       // floats per channel in dw LDS (9*56=504 + pad 4)

typedef __attribute__((ext_vector_type(8))) short s16x8;
typedef __attribute__((ext_vector_type(4))) float f32x4;
typedef unsigned int u32;
typedef unsigned short u16;

__device__ __forceinline__ void async_copy16(void* lds, const void* g) {
    __builtin_amdgcn_global_load_lds((const __attribute__((address_space(1))) unsigned int*)g,
                                     (__attribute__((address_space(3))) unsigned int*)lds,
                                     16, 0, 0);
}

__device__ __forceinline__ u16 bf16_bits(float f) {
    __hip_bfloat16 h = __float2bfloat16(f);
    union { __hip_bfloat16 h; u16 u; } cv; cv.h = h; return cv.u;
}

// ---------------- prep: W fp32 -> bf16, fold BN2+bias into (scale,shift), zero max buffers ----------------
__global__ __launch_bounds__(256) void prep_kernel(
    const float* __restrict__ pww, const float* __restrict__ pwb,
    const float* __restrict__ g2, const float* __restrict__ b2,
    const float* __restrict__ m2, const float* __restrict__ v2,
    u16* __restrict__ wb, float2* __restrict__ scsh,
    u32* __restrict__ omax, u32* __restrict__ dwmax)
{
    const int gid = blockIdx.x * 256 + threadIdx.x;     // 16384 threads
    const int base = gid * 8;                           // covers 131072 = COUT*CIN
    const float4 a = *(const float4*)(pww + base);
    const float4 b = *(const float4*)(pww + base + 4);
    union { u16 u[8]; s16x8 v; } pk;
    pk.u[0] = bf16_bits(a.x); pk.u[1] = bf16_bits(a.y);
    pk.u[2] = bf16_bits(a.z); pk.u[3] = bf16_bits(a.w);
    pk.u[4] = bf16_bits(b.x); pk.u[5] = bf16_bits(b.y);
    pk.u[6] = bf16_bits(b.z); pk.u[7] = bf16_bits(b.w);
    *(s16x8*)(wb + base) = pk.v;
    omax[gid] = 0u;                                     // NBATCH*COUT = 16384
    if (gid < NBATCH * CIN) dwmax[gid] = 0u;            // 8192
    if (gid < COUT) {
        const float sc = g2[gid] * rsqrtf(v2[gid] + EPS);
        const float sh = fmaf(-m2[gid], sc, b2[gid]) + pwb[gid] * sc;
        scsh[gid] = make_float2(sc, sh);
    }
}

// ---------------- dw: LDS-staged 3x3 depthwise + BN1 + ReLU -> y NHWC bf16 + per-(n,c) max ----------------
__global__ __launch_bounds__(256) void dw_kernel(
    const float* __restrict__ x, const float* __restrict__ dww, const float* __restrict__ dwb,
    const float* __restrict__ g1, const float* __restrict__ b1,
    const float* __restrict__ m1, const float* __restrict__ v1,
    u16* __restrict__ y, u32* __restrict__ dwmax)
{
    __shared__ float xs[CG * CPITCH];   // [c][local row 0..8][px]

    const int bid = blockIdx.x;
    const int cg = bid & 7;             // channel group (8)
    const int hs = (bid >> 3) & 7;      // strip (8)
    const int n  = bid >> 6;            // batch (32)
    const int t  = threadIdx.x;

    const int g0     = hs * 7 - 1;
    const int gstart = (g0 < 0) ? 0 : g0;
    const int gend   = (hs * 7 + 7 > 55) ? 55 : hs * 7 + 7;
    const int nrows  = gend - gstart + 1;          // 8 or 9
    const int dst0   = gstart - g0;
    const int cnt4   = nrows * 14;

    if (hs == 0) {
        for (int i = t; i < CG * 14; i += 256) {
            const int c = i / 14, j = i - c * 14;
            *(float4*)&xs[c * CPITCH + j * 4] = make_float4(0.f, 0.f, 0.f, 0.f);
        }
    } else if (hs == 7) {
        for (int i = t; i < CG * 14; i += 256) {
            const int c = i / 14, j = i - c * 14;
            *(float4*)&xs[c * CPITCH + 8 * 56 + j * 4] = make_float4(0.f, 0.f, 0.f, 0.f);
        }
    }

    {
        const float* gbase = x + (size_t)(n * CIN + cg * CG) * HW + gstart * 56;
        const int half = t >> 7;
        const int i4 = t & 127;
        for (int cc = 0; cc < 16; ++cc) {
            const int c = cc * 2 + half;
            if (i4 < cnt4) {
                const float4 v = *(const float4*)(gbase + (size_t)c * HW + i4 * 4);
                *(float4*)&xs[c * CPITCH + dst0 * 56 + i4 * 4] = v;
            }
        }
    }
    __syncthreads();

    const int r = t >> 5;
    const int c = t & 31;
    float vmax = 0.f;
    if (r < 7) {
        const int ch = cg * CG + c;
        const float* wp = dww + ch * 9;
        const float w00 = wp[0], w01 = wp[1], w02 = wp[2];
        const float w10 = wp[3], w11 = wp[4], w12 = wp[5];
        const float w20 = wp[6], w21 = wp[7], w22 = wp[8];
        const float sc = g1[ch] * rsqrtf(v1[ch] + EPS);
        const float sh = fmaf(-m1[ch], sc, b1[ch]) + dwb[ch] * sc;

        const float* rm = &xs[c * CPITCH + r * 56];
        const float* r0 = rm + 56;
        const float* rp = rm + 112;
        const int grow = hs * 7 + r;
        u16* yo = y + (size_t)(n * HW + grow * WW) * CIN + ch;

        float4 cm = *(const float4*)rm;
        float4 c0 = *(const float4*)r0;
        float4 cp = *(const float4*)rp;
        float lm = 0.f, l0 = 0.f, lp = 0.f;

        for (int chk = 0; chk < 14; ++chk) {
            float4 nm, n0, np;
            if (chk < 13) {
                nm = *(const float4*)(rm + 4 * chk + 4);
                n0 = *(const float4*)(r0 + 4 * chk + 4);
                np = *(const float4*)(rp + 4 * chk + 4);
            } else {
                nm = n0 = np = make_float4(0.f, 0.f, 0.f, 0.f);
            }
            float s0 = w00*lm   + w01*cm.x + w02*cm.y
                     + w10*l0   + w11*c0.x + w12*c0.y
                     + w20*lp   + w21*cp.x + w22*cp.y;
            float s1 = w00*cm.x + w01*cm.y + w02*cm.z
                     + w10*c0.x + w11*c0.y + w12*c0.z
                     + w20*cp.x + w21*cp.y + w22*cp.z;
            float s2 = w00*cm.y + w01*cm.z + w02*cm.w
                     + w10*c0.y + w11*c0.z + w12*c0.w
                     + w20*cp.y + w21*cp.z + w22*cp.w;
            float s3 = w00*cm.z + w01*cm.w + w02*nm.x
                     + w10*c0.z + w11*c0.w + w12*n0.x
                     + w20*cp.z + w21*cp.w + w22*np.x;
            const float v0 = fmaxf(fmaf(s0, sc, sh), 0.f);
            const float v1s = fmaxf(fmaf(s1, sc, sh), 0.f);
            const float v2s = fmaxf(fmaf(s2, sc, sh), 0.f);
            const float v3 = fmaxf(fmaf(s3, sc, sh), 0.f);
            vmax = fmaxf(fmaxf(vmax, fmaxf(v0, v1s)), fmaxf(v2s, v3));
            yo[(4 * chk + 0) * CIN] = bf16_bits(v0);
            yo[(4 * chk + 1) * CIN] = bf16_bits(v1s);
            yo[(4 * chk + 2) * CIN] = bf16_bits(v2s);
            yo[(4 * chk + 3) * CIN] = bf16_bits(v3);
            lm = cm.w; l0 = c0.w; lp = cp.w;
            cm = nm; c0 = n0; cp = np;
        }
    }
    vmax = fmaxf(vmax, __shfl_xor(vmax, 32));
    if ((t & 32) == 0)
        atomicMax(&dwmax[n * CIN + cg * CG + c], __float_as_uint(vmax));
}

// ---------------- dw channel cut fixup ----------------
__global__ __launch_bounds__(64) void dwcut_kernel(const u32* __restrict__ dwmax, u16* __restrict__ y)
{
    const int b = blockIdx.x;          // n*CIN + c
    if (__uint_as_float(dwmax[b]) >= DW_TH) return;
    const int n = b >> 8, c = b & 255;
    for (int hw = threadIdx.x; hw < HW; hw += 64)
        y[(size_t)(n * HW + hw) * CIN + c] = 0;
}

// ---------------- pw v2: m97-style 128x128 bf16 MFMA GEMM, 4 waves 2x2, 4x4 frags ----------------
// grid (25 hw-tiles [last padded], 4 o-tiles, 32 n); BK=32; LDS 16 KB
__global__ __launch_bounds__(256) void pw_kernel(
    const u16* __restrict__ y, const u16* __restrict__ wb,
    const float2* __restrict__ scsh,
    float* __restrict__ out, u32* __restrict__ omax)
{
    __shared__ u16 Wt[128 * 32];   // [o][k], pitch 64B
    __shared__ u16 Yt[128 * 32];   // [hw][k], pitch 64B

    const int hwt = blockIdx.x, ot = blockIdx.y, n = blockIdx.z;
    const int t = threadIdx.x;
    const int w = t >> 6;          // wave 0..3, arranged 2(o) x 2(hw)
    const int l = t & 63;
    const int lo = l & 15, hi = l >> 4;
    const int wo = (w >> 1) * 64;  // wave o-offset in tile
    const int wh = (w & 1) * 64;   // wave hw-offset in tile

    const int o_blk = ot * 128;

    // staging: wave w fills rows [w*32, w*32+32) of each tile, 2 instrs of 16 rows
    const int srow = w * 32 + (l >> 2);
    const u16* wg = wb + (size_t)(o_blk + srow) * CIN + (l & 3) * 8;
    int yr0 = hwt * 128 + srow;       if (yr0 > HW - 1) yr0 = HW - 1;   // pad clamp
    int yr1 = hwt * 128 + srow + 16;  if (yr1 > HW - 1) yr1 = HW - 1;
    const u16* yg0 = y + (size_t)(n * HW + yr0) * CIN + (l & 3) * 8;
    const u16* yg1 = y + (size_t)(n * HW + yr1) * CIN + (l & 3) * 8;
    char* WtB = (char*)Wt;
    char* YtB = (char*)Yt;

    f32x4 acc[4][4];
#pragma unroll
    for (int i = 0; i < 4; ++i)
#pragma unroll
        for (int j = 0; j < 4; ++j) acc[i][j] = (f32x4){0.f, 0.f, 0.f, 0.f};

    for (int k0 = 0; k0 < CIN; k0 += 32) {
        async_copy16(WtB + (w * 32) * 64,      wg + k0);
        async_copy16(WtB + (w * 32 + 16) * 64, wg + k0 + (size_t)16 * CIN);
        async_copy16(YtB + (w * 32) * 64,      yg0 + k0);
        async_copy16(YtB + (w * 32 + 16) * 64, yg1 + k0);
        __syncthreads();

        s16x8 af[4], bf[4];
#pragma unroll
        for (int so = 0; so < 4; ++so)
            af[so] = *(const s16x8*)(WtB + (wo + so * 16 + lo) * 64 + hi * 16);
#pragma unroll
        for (int sj = 0; sj < 4; ++sj)
            bf[sj] = *(const s16x8*)(YtB + (wh + sj * 16 + lo) * 64 + hi * 16);
#pragma unroll
        for (int so = 0; so < 4; ++so)
#pragma unroll
            for (int sj = 0; sj < 4; ++sj)
                acc[so][sj] = __builtin_amdgcn_mfma_f32_16x16x32_bf16(af[so], bf[sj], acc[so][sj], 0, 0, 0);
        __syncthreads();
    }

    // last hw tile: hw 3072..3199; valid < 3136 == exactly the wh=0 half. Wave-uniform guard.
    if (hwt == 24 && (w & 1)) return;

    // epilogue: C/D col=lane&15 (hw), row=(lane>>4)*4+reg (o)
#pragma unroll
    for (int so = 0; so < 4; ++so) {
#pragma unroll
        for (int r = 0; r < 4; ++r) {
            const int o = o_blk + wo + so * 16 + hi * 4 + r;
            const float2 ss = scsh[o];
            float m = 0.f;
            float* op = out + (size_t)(n * COUT + o) * HW + hwt * 128 + wh + lo;
#pragma unroll
            for (int sj = 0; sj < 4; ++sj) {
                const float v = fmaxf(fmaf(acc[so][sj][r], ss.x, ss.y), 0.f);
                op[sj * 16] = v;
                m = fmaxf(m, v);
            }
            m = fmaxf(m, __shfl_xor(m, 1));
            m = fmaxf(m, __shfl_xor(m, 2));
            m = fmaxf(m, __shfl_xor(m, 4));
            m = fmaxf(m, __shfl_xor(m, 8));
            if (lo == 0) atomicMax(&omax[n * COUT + o], __float_as_uint(m));
        }
    }
}

// ---------------- pw channel cut fixup ----------------
__global__ __launch_bounds__(256) void pwcut_kernel(const u32* __restrict__ omax, float* __restrict__ out)
{
    const int b = blockIdx.x;   // n*COUT + o
    if (__uint_as_float(omax[b]) >= PW_TH) return;
    float* p = out + (size_t)b * HW;
    for (int i = threadIdx.x; i < HW; i += 256) p[i] = 0.0f;
}

extern "C" void kernel_launch(void* const* d_in, const int* in_sizes, int n_in,
                              void* d_out, int out_size, void* d_ws, size_t ws_size,
                              hipStream_t stream) {
    const float* x   = (const float*)d_in[0];
    const float* dww = (const float*)d_in[1];
    const float* dwb = (const float*)d_in[2];
    const float* g1  = (const float*)d_in[3];
    const float* b1  = (const float*)d_in[4];
    const float* m1  = (const float*)d_in[5];
    const float* v1  = (const float*)d_in[6];
    const float* pww = (const float*)d_in[7];
    const float* pwb = (const float*)d_in[8];
    const float* g2  = (const float*)d_in[9];
    const float* b2  = (const float*)d_in[10];
    const float* m2  = (const float*)d_in[11];
    const float* v2  = (const float*)d_in[12];
    float* out = (float*)d_out;

    // ws layout: [0,64K) pw omax; [64K,96K) dw max; [96K,100K) scsh; [128K,384K) W bf16; [1M,...) y NHWC bf16
    u32*    omax  = (u32*)d_ws;
    u32*    dwmax = (u32*)((char*)d_ws + (64 << 10));
    float2* scsh  = (float2*)((char*)d_ws + (96 << 10));
    u16*    wbf   = (u16*)((char*)d_ws + (128 << 10));
    u16*    y     = (u16*)((char*)d_ws + (1 << 20));

    prep_kernel<<<64, 256, 0, stream>>>(pww, pwb, g2, b2, m2, v2, wbf, scsh, omax, dwmax);
    dw_kernel<<<NBATCH * 8 * 8, 256, 0, stream>>>(x, dww, dwb, g1, b1, m1, v1, y, dwmax);
    dwcut_kernel<<<NBATCH * CIN, 64, 0, stream>>>(dwmax, y);
    dim3 gpw(25, COUT / 128, NBATCH);   // 25 (24.5 padded), 4, 32
    pw_kernel<<<gpw, 256, 0, stream>>>(y, wbf, scsh, out, omax);
    pwcut_kernel<<<NBATCH * COUT, 256, 0, stream>>>(omax, out);
}